// Round 7
// baseline (452.853 us; speedup 1.0000x reference)
//
#include <hip/hip_runtime.h>

typedef _Float16 f16x8 __attribute__((ext_vector_type(8)));
typedef float    f32x4 __attribute__((ext_vector_type(4)));
typedef int      i32x4 __attribute__((ext_vector_type(4)));

#define S_LEN 2048
#define D_KH  64
#define NBH   32                       // B*H
#define QTILE 16
#define NBLK  (NBH * (S_LEN / QTILE))  // 4096
#define THREADS 512                    // 8 waves; wave owns a 256-key strip
#define QK_ELEMS (NBH * S_LEN * D_KH)

__device__ __forceinline__ f16x8 cvt8(const float4 a, const float4 b) {
  f16x8 r;
  r[0] = (_Float16)a.x; r[1] = (_Float16)a.y;
  r[2] = (_Float16)a.z; r[3] = (_Float16)a.w;
  r[4] = (_Float16)b.x; r[5] = (_Float16)b.y;
  r[6] = (_Float16)b.z; r[7] = (_Float16)b.w;
  return r;
}

// Prep: K -> f16, q -> f16 pre-scaled by 1/sqrt(64).
__global__ __launch_bounds__(256) void cvt_qk_kernel(
    const float* __restrict__ q, const float* __restrict__ kmat,
    _Float16* __restrict__ qh, _Float16* __restrict__ kh) {
  const long long idx = ((long long)blockIdx.x * 256 + threadIdx.x) * 8;
  float4 q0 = *(const float4*)(q + idx);
  float4 q1 = *(const float4*)(q + idx + 4);
  const float s = 0.125f;
  q0.x *= s; q0.y *= s; q0.z *= s; q0.w *= s;
  q1.x *= s; q1.y *= s; q1.z *= s; q1.w *= s;
  *(f16x8*)(qh + idx) = cvt8(q0, q1);
  const float4 k0 = *(const float4*)(kmat + idx);
  const float4 k1 = *(const float4*)(kmat + idx + 4);
  *(f16x8*)(kh + idx) = cvt8(k0, k1);
}

__device__ __forceinline__ void ms_combine(float& m, float& s,
                                           const float m2, const float s2) {
  const float M = fmaxf(m, m2);
  s = s * __expf(m - M) + s2 * __expf(m2 - M);
  m = M;
}

// Two-pass recompute scheme, swapped operands D = mfma(K, Q):
// lane (lo=l&15, g=l>>4) reg r holds score[key=(w<<8)+(kt<<4)+(g<<2)+r][qrow=lo]
// (layout verified by the passing R3 run). Pass 1: online (m,s) per lane +
// pack 64 mask bits into 2 u32; tiny LDS merge; pass 2: recompute scores,
// store normalized probs. No score storage -> 1 KiB LDS, ~60 VGPR, 4 blk/CU.
template <bool F16>
__global__ __launch_bounds__(THREADS, 8) void sdpa_probs_kernel(
    const float* __restrict__ qf, const float* __restrict__ kf,
    const _Float16* __restrict__ qh, const _Float16* __restrict__ kh,
    const int* __restrict__ mask, float* __restrict__ out) {
  // XCD swizzle: 512 consecutive nb per XCD -> 4 heads' f16 panels hot in L2.
  const int bid = (int)blockIdx.x;
  const int nb  = (bid & 7) * (NBLK / 8) + (bid >> 3);
  const int bh  = nb >> 7;
  const int qt  = nb & 127;

  __shared__ float smax[8][QTILE];
  __shared__ float ssum[8][QTILE];

  const int tid = (int)threadIdx.x;
  const int w   = tid >> 6;   // wave 0..7: keys [256w, 256w+256)
  const int l   = tid & 63;
  const int lo  = l & 15;     // q-row within tile
  const int g   = l >> 4;

  const size_t qk_bh = (size_t)bh * S_LEN * D_KH;
  const size_t obh   = (size_t)bh * S_LEN * S_LEN;
  const int    qrow  = qt * QTILE + lo;
  const int    kbase = (w << 8) + (g << 2);   // this lane's first key

  // ---- B fragment: Q row (pre-scaled) ----
  f16x8 qb0, qb1;
  if constexpr (F16) {
    const _Float16* qp = qh + qk_bh + (size_t)qrow * D_KH + (g << 3);
    qb0 = *(const f16x8*)qp;
    qb1 = *(const f16x8*)(qp + 32);
  } else {
    const float* qp = qf + qk_bh + (size_t)qrow * D_KH + (g << 3);
    float4 t0 = *(const float4*)(qp);
    float4 t1 = *(const float4*)(qp + 4);
    float4 t2 = *(const float4*)(qp + 32);
    float4 t3 = *(const float4*)(qp + 36);
    const float sc = 0.125f;
    t0.x *= sc; t0.y *= sc; t0.z *= sc; t0.w *= sc;
    t1.x *= sc; t1.y *= sc; t1.z *= sc; t1.w *= sc;
    t2.x *= sc; t2.y *= sc; t2.z *= sc; t2.w *= sc;
    t3.x *= sc; t3.y *= sc; t3.z *= sc; t3.w *= sc;
    qb0 = cvt8(t0, t1);
    qb1 = cvt8(t2, t3);
  }

  // ---- Pass 1: online (m,s) + mask-bit packing; scores discarded ----
  float m = -3.0e38f, s = 0.f;
  unsigned pm0 = 0u, pm1 = 0u;
  const int* mrow = mask + obh + (size_t)qrow * S_LEN + kbase;

  #pragma unroll 2
  for (int kt = 0; kt < 16; ++kt) {
    const int keyA = (w << 8) + (kt << 4) + lo;
    f16x8 ka0, ka1;
    if constexpr (F16) {
      const _Float16* kp = kh + qk_bh + (size_t)keyA * D_KH + (g << 3);
      ka0 = *(const f16x8*)kp;
      ka1 = *(const f16x8*)(kp + 32);
    } else {
      const float* kp = kf + qk_bh + (size_t)keyA * D_KH + (g << 3);
      ka0 = cvt8(*(const float4*)(kp), *(const float4*)(kp + 4));
      ka1 = cvt8(*(const float4*)(kp + 32), *(const float4*)(kp + 36));
    }
    const i32x4 mv = __builtin_nontemporal_load((const i32x4*)(mrow + (kt << 4)));
    f32x4 acc = {0.f, 0.f, 0.f, 0.f};
    acc = __builtin_amdgcn_mfma_f32_16x16x32_f16(ka0, qb0, acc, 0, 0, 0);
    acc = __builtin_amdgcn_mfma_f32_16x16x32_f16(ka1, qb1, acc, 0, 0, 0);

    const unsigned bits = (mv.x ? 1u : 0u) | (mv.y ? 2u : 0u)
                        | (mv.z ? 4u : 0u) | (mv.w ? 8u : 0u);
    if (kt < 8) pm0 |= bits << (4 * kt); else pm1 |= bits << (4 * (kt - 8));

    // Online max (raw, pre-mask: any M >= true masked max is safe) + sum.
    const float t = fmaxf(fmaxf(acc[0], acc[1]), fmaxf(acc[2], acc[3]));
    const float M = fmaxf(m, t);
    s *= __expf(m - M);
    m = M;
    s += (bits & 1u) ? 0.f : __expf(acc[0] - m);
    s += (bits & 2u) ? 0.f : __expf(acc[1] - m);
    s += (bits & 4u) ? 0.f : __expf(acc[2] - m);
    s += (bits & 8u) ? 0.f : __expf(acc[3] - m);
  }

  // Merge (m,s) across the 4 g-groups (lanes lo, lo+16, lo+32, lo+48).
  {
    float m2 = __shfl_xor(m, 16, 64), s2 = __shfl_xor(s, 16, 64);
    ms_combine(m, s, m2, s2);
    m2 = __shfl_xor(m, 32, 64); s2 = __shfl_xor(s, 32, 64);
    ms_combine(m, s, m2, s2);
  }
  if (l < 16) { smax[w][lo] = m; ssum[w][lo] = s; }
  __syncthreads();

  // Global row (M, 1/S): 8 broadcast LDS reads per lane.
  float M = -3.0e38f, S = 0.f;
  #pragma unroll
  for (int j = 0; j < 8; ++j) ms_combine(M, S, smax[j][lo], ssum[j][lo]);
  const float inv = 1.0f / S;

  // ---- Pass 2: recompute scores, normalize, store ----
  float* op = out + obh + (size_t)qrow * S_LEN + kbase;
  #pragma unroll 2
  for (int kt = 0; kt < 16; ++kt) {
    const int keyA = (w << 8) + (kt << 4) + lo;
    f16x8 ka0, ka1;
    if constexpr (F16) {
      const _Float16* kp = kh + qk_bh + (size_t)keyA * D_KH + (g << 3);
      ka0 = *(const f16x8*)kp;
      ka1 = *(const f16x8*)(kp + 32);
    } else {
      const float* kp = kf + qk_bh + (size_t)keyA * D_KH + (g << 3);
      ka0 = cvt8(*(const float4*)(kp), *(const float4*)(kp + 4));
      ka1 = cvt8(*(const float4*)(kp + 32), *(const float4*)(kp + 36));
    }
    f32x4 acc = {0.f, 0.f, 0.f, 0.f};
    acc = __builtin_amdgcn_mfma_f32_16x16x32_f16(ka0, qb0, acc, 0, 0, 0);
    acc = __builtin_amdgcn_mfma_f32_16x16x32_f16(ka1, qb1, acc, 0, 0, 0);
    const unsigned bits = (kt < 8) ? (pm0 >> (4 * kt)) : (pm1 >> (4 * (kt - 8)));
    f32x4 o = { (bits & 1u) ? 0.f : __expf(acc[0] - M) * inv,
                (bits & 2u) ? 0.f : __expf(acc[1] - M) * inv,
                (bits & 4u) ? 0.f : __expf(acc[2] - M) * inv,
                (bits & 8u) ? 0.f : __expf(acc[3] - M) * inv };
    __builtin_nontemporal_store(o, (f32x4*)(op + (kt << 4)));
  }
}

extern "C" void kernel_launch(void* const* d_in, const int* in_sizes, int n_in,
                              void* d_out, int out_size, void* d_ws, size_t ws_size,
                              hipStream_t stream) {
  const float* q    = (const float*)d_in[0];
  const float* kmat = (const float*)d_in[1];
  // d_in[2] = v, unused (reference stops at softmax)
  const int*   mask = (const int*)d_in[3];
  float*       out  = (float*)d_out;

  const size_t need = (size_t)QK_ELEMS * 2 * sizeof(_Float16);
  if (ws_size >= need) {
    _Float16* qh = (_Float16*)d_ws;
    _Float16* kh = qh + QK_ELEMS;
    cvt_qk_kernel<<<dim3(QK_ELEMS / 8 / 256), dim3(256), 0, stream>>>(q, kmat, qh, kh);
    sdpa_probs_kernel<true><<<dim3(NBLK), dim3(THREADS), 0, stream>>>(
        nullptr, nullptr, qh, kh, mask, out);
  } else {
    sdpa_probs_kernel<false><<<dim3(NBLK), dim3(THREADS), 0, stream>>>(
        q, kmat, nullptr, nullptr, mask, out);
  }
}

// Round 8
// 250.329 us; speedup vs baseline: 1.8090x; 1.8090x over previous
//
#include <hip/hip_runtime.h>

typedef _Float16 f16x8 __attribute__((ext_vector_type(8)));
typedef _Float16 f16x4 __attribute__((ext_vector_type(4)));
typedef float    f32x4 __attribute__((ext_vector_type(4)));
typedef int      i32x4 __attribute__((ext_vector_type(4)));

#define S_LEN 2048
#define D_KH  64
#define NBH   32                       // B*H
#define QTILE 16
#define NBLK  (NBH * (S_LEN / QTILE))  // 4096
#define THREADS 512                    // 8 waves
#define QK_ELEMS (NBH * S_LEN * D_KH)
#define BITS_WORDS (NBH * S_LEN * 64)  // one u32 per (row, lane) = 16 MiB

__device__ __forceinline__ f16x8 cvt8(const float4 a, const float4 b) {
  f16x8 r;
  r[0] = (_Float16)a.x; r[1] = (_Float16)a.y;
  r[2] = (_Float16)a.z; r[3] = (_Float16)a.w;
  r[4] = (_Float16)b.x; r[5] = (_Float16)b.y;
  r[6] = (_Float16)b.z; r[7] = (_Float16)b.w;
  return r;
}

// Prep 1: K -> f16, q -> f16 pre-scaled by 1/sqrt(64).
__global__ __launch_bounds__(256) void cvt_qk_kernel(
    const float* __restrict__ q, const float* __restrict__ kmat,
    _Float16* __restrict__ qh, _Float16* __restrict__ kh) {
  const long long idx = ((long long)blockIdx.x * 256 + threadIdx.x) * 8;
  float4 q0 = *(const float4*)(q + idx);
  float4 q1 = *(const float4*)(q + idx + 4);
  const float s = 0.125f;
  q0.x *= s; q0.y *= s; q0.z *= s; q0.w *= s;
  q1.x *= s; q1.y *= s; q1.z *= s; q1.w *= s;
  *(f16x8*)(qh + idx) = cvt8(q0, q1);
  const float4 k0 = *(const float4*)(kmat + idx);
  const float4 k1 = *(const float4*)(kmat + idx + 4);
  *(f16x8*)(kh + idx) = cvt8(k0, k1);
}

// Prep 2: pack int32 mask -> per-(row,lane) u32 bitfield. Word (grow, lane):
// bit (4i+j) = mask[grow][(i<<8)+(lane<<2)+j]. Pure read stream (512 MiB in,
// 16 MiB out); per wave per i the lanes cover a contiguous 1 KiB.
__global__ __launch_bounds__(256) void pack_mask_kernel(
    const int* __restrict__ mask, unsigned* __restrict__ bits) {
  const int t    = (int)blockIdx.x * 256 + (int)threadIdx.x;
  const int lane = t & 63;
  const long long grow = t >> 6;            // global row: bh*2048 + row
  const int* mrow = mask + grow * S_LEN + (lane << 2);
  unsigned pm = 0u;
  #pragma unroll
  for (int i = 0; i < 8; ++i) {
    const i32x4 mv = __builtin_nontemporal_load((const i32x4*)(mrow + (i << 8)));
    pm |= ((mv.x ? 1u : 0u) | (mv.y ? 2u : 0u) |
           (mv.z ? 4u : 0u) | (mv.w ? 8u : 0u)) << (4 * i);
  }
  bits[t] = pm;
}

// 3-pass softmax over an LDS f16 score row; mask as 32-bit field
// (bit 4i+j = col (i<<8)+(l<<2)+j). Proven correct in R6's run.
__device__ __forceinline__ void softmax_row_packed(
    const _Float16* __restrict__ srow, const unsigned pm, const int physx,
    const int l, float* __restrict__ op) {
  float mx = -3.0e38f;
  #pragma unroll
  for (int i = 0; i < 8; ++i) {
    const int off = (((i << 8) + (l << 2))) ^ physx;
    const f16x4 h = *(const f16x4*)&srow[off];
    const unsigned b = pm >> (4 * i);
    mx = fmaxf(mx, (b & 1u) ? -1.0e9f : (float)h[0]);
    mx = fmaxf(mx, (b & 2u) ? -1.0e9f : (float)h[1]);
    mx = fmaxf(mx, (b & 4u) ? -1.0e9f : (float)h[2]);
    mx = fmaxf(mx, (b & 8u) ? -1.0e9f : (float)h[3]);
  }
  #pragma unroll
  for (int off = 32; off > 0; off >>= 1)
    mx = fmaxf(mx, __shfl_xor(mx, off, 64));
  float sum = 0.f;
  #pragma unroll
  for (int i = 0; i < 8; ++i) {
    const int off = (((i << 8) + (l << 2))) ^ physx;
    const f16x4 h = *(const f16x4*)&srow[off];
    const unsigned b = pm >> (4 * i);
    sum += (b & 1u) ? 0.f : __expf((float)h[0] - mx);
    sum += (b & 2u) ? 0.f : __expf((float)h[1] - mx);
    sum += (b & 4u) ? 0.f : __expf((float)h[2] - mx);
    sum += (b & 8u) ? 0.f : __expf((float)h[3] - mx);
  }
  #pragma unroll
  for (int off = 32; off > 0; off >>= 1)
    sum += __shfl_xor(sum, off, 64);
  const float inv = 1.0f / sum;
  #pragma unroll
  for (int i = 0; i < 8; ++i) {
    const int col = (i << 8) + (l << 2);
    const f16x4 h = *(const f16x4*)&srow[col ^ physx];
    const unsigned b = pm >> (4 * i);
    f32x4 o = { (b & 1u) ? 0.f : __expf((float)h[0] - mx) * inv,
                (b & 2u) ? 0.f : __expf((float)h[1] - mx) * inv,
                (b & 4u) ? 0.f : __expf((float)h[2] - mx) * inv,
                (b & 8u) ? 0.f : __expf((float)h[3] - mx) * inv };
    __builtin_nontemporal_store(o, (f32x4*)(op + col));
  }
}

// Main: R4's proven structure (236 µs), masks replaced by the bitfield ->
// HBM is ~97% pure prob-writes. F16=false fallback packs masks inline.
template <bool F16>
__global__ __launch_bounds__(THREADS, 4) void sdpa_probs_kernel(
    const float* __restrict__ qf, const float* __restrict__ kf,
    const _Float16* __restrict__ qh, const _Float16* __restrict__ kh,
    const int* __restrict__ mask, const unsigned* __restrict__ bits,
    float* __restrict__ out) {
  // XCD swizzle: 512 consecutive nb per XCD -> 4 heads' f16 panels hot in L2.
  const int bid = (int)blockIdx.x;
  const int nb  = (bid & 7) * (NBLK / 8) + (bid >> 3);
  const int bh  = nb >> 7;
  const int qt  = nb & 127;

  __shared__ _Float16 sc[QTILE][S_LEN];  // 64 KiB score strip

  const int tid   = (int)threadIdx.x;
  const int w     = tid >> 6;   // wave 0..7
  const int l     = tid & 63;
  const int lo    = l & 15;
  const int g     = l >> 4;
  const int dbase = g << 3;

  const size_t qk_bh = (size_t)bh * S_LEN * D_KH;
  const size_t obh   = (size_t)bh * S_LEN * S_LEN;

  const int rowA = w << 1, rowB = rowA | 1;  // wave w owns rows 2w, 2w+1
  const size_t orowA = obh + (size_t)(qt * QTILE + rowA) * S_LEN;
  const size_t orowB = obh + (size_t)(qt * QTILE + rowB) * S_LEN;

  // ---- Mask bits: one u32 per row per lane (256 B per wave, L2-cheap) ----
  unsigned pmA, pmB;
  if constexpr (F16) {
    const unsigned* brow = bits + ((size_t)bh * S_LEN + qt * QTILE) * 64;
    pmA = brow[rowA * 64 + l];
    pmB = brow[rowB * 64 + l];
  }

  // ---- A fragments: q rows (pre-scaled) ----
  f16x8 a0, a1;
  if constexpr (F16) {
    const _Float16* qp = qh + qk_bh + (size_t)(qt * QTILE + lo) * D_KH + dbase;
    a0 = *(const f16x8*)qp;
    a1 = *(const f16x8*)(qp + 32);
  } else {
    const float* qp = qf + qk_bh + (size_t)(qt * QTILE + lo) * D_KH;
    float4 t0 = *(const float4*)(qp + dbase);
    float4 t1 = *(const float4*)(qp + dbase + 4);
    float4 t2 = *(const float4*)(qp + dbase + 32);
    float4 t3 = *(const float4*)(qp + dbase + 36);
    const float s = 0.125f;
    t0.x *= s; t0.y *= s; t0.z *= s; t0.w *= s;
    t1.x *= s; t1.y *= s; t1.z *= s; t1.w *= s;
    t2.x *= s; t2.y *= s; t2.z *= s; t2.w *= s;
    t3.x *= s; t3.y *= s; t3.z *= s; t3.w *= s;
    a0 = cvt8(t0, t1);
    a1 = cvt8(t2, t3);
  }

  // ---- Phase 1: scores via f16 MFMA; wave w owns keys [256w, 256w+256) ----
  #pragma unroll 2
  for (int kt = 0; kt < 16; ++kt) {
    const int kcol = (w << 8) + (kt << 4) + lo;
    f16x8 b0, b1;
    if constexpr (F16) {
      const _Float16* kp = kh + qk_bh + (size_t)kcol * D_KH + dbase;
      b0 = *(const f16x8*)kp;
      b1 = *(const f16x8*)(kp + 32);
    } else {
      const float* kp = kf + qk_bh + (size_t)kcol * D_KH + dbase;
      b0 = cvt8(*(const float4*)(kp), *(const float4*)(kp + 4));
      b1 = cvt8(*(const float4*)(kp + 32), *(const float4*)(kp + 36));
    }
    f32x4 acc = {0.f, 0.f, 0.f, 0.f};
    acc = __builtin_amdgcn_mfma_f32_16x16x32_f16(a0, b0, acc, 0, 0, 0);
    acc = __builtin_amdgcn_mfma_f32_16x16x32_f16(a1, b1, acc, 0, 0, 0);
    // D layout: row = 4g+r, col = lo. XOR-swizzle col bit4 by g -> 32 banks,
    // 2 lanes/bank (free).
    const int phys = kcol ^ (g << 4);
    #pragma unroll
    for (int r = 0; r < 4; ++r)
      sc[(g << 2) + r][phys] = (_Float16)acc[r];
  }

  if constexpr (!F16) {
    // Fallback: pack raw masks inline (arrives under phase 1's tail).
    pmA = 0u; pmB = 0u;
    const int* mpA = mask + orowA + (l << 2);
    const int* mpB = mask + orowB + (l << 2);
    #pragma unroll
    for (int i = 0; i < 8; ++i) {
      const i32x4 a = __builtin_nontemporal_load((const i32x4*)(mpA + (i << 8)));
      const i32x4 b = __builtin_nontemporal_load((const i32x4*)(mpB + (i << 8)));
      pmA |= ((a.x ? 1u : 0u) | (a.y ? 2u : 0u) |
              (a.z ? 4u : 0u) | (a.w ? 8u : 0u)) << (4 * i);
      pmB |= ((b.x ? 1u : 0u) | (b.y ? 2u : 0u) |
              (b.z ? 4u : 0u) | (b.w ? 8u : 0u)) << (4 * i);
    }
  }

  __syncthreads();

  // ---- Phase 2: per-row softmax + pure store stream ----
  const int physx = (w >> 1) << 4;   // rowA>>2 == rowB>>2 == w>>1
  softmax_row_packed(&sc[rowA][0], pmA, physx, l, out + orowA);
  softmax_row_packed(&sc[rowB][0], pmB, physx, l, out + orowB);
}

extern "C" void kernel_launch(void* const* d_in, const int* in_sizes, int n_in,
                              void* d_out, int out_size, void* d_ws, size_t ws_size,
                              hipStream_t stream) {
  const float* q    = (const float*)d_in[0];
  const float* kmat = (const float*)d_in[1];
  // d_in[2] = v, unused (reference stops at softmax)
  const int*   mask = (const int*)d_in[3];
  float*       out  = (float*)d_out;

  const size_t need = (size_t)QK_ELEMS * 2 * sizeof(_Float16)
                    + (size_t)BITS_WORDS * sizeof(unsigned);
  if (ws_size >= need) {
    _Float16* qh   = (_Float16*)d_ws;
    _Float16* kh   = qh + QK_ELEMS;
    unsigned* bits = (unsigned*)(kh + QK_ELEMS);
    cvt_qk_kernel<<<dim3(QK_ELEMS / 8 / 256), dim3(256), 0, stream>>>(q, kmat, qh, kh);
    pack_mask_kernel<<<dim3(BITS_WORDS / 256), dim3(256), 0, stream>>>(mask, bits);
    sdpa_probs_kernel<true><<<dim3(NBLK), dim3(THREADS), 0, stream>>>(
        nullptr, nullptr, qh, kh, nullptr, bits, out);
  } else {
    sdpa_probs_kernel<false><<<dim3(NBLK), dim3(THREADS), 0, stream>>>(
        q, kmat, nullptr, nullptr, mask, nullptr, out);
  }
}